// Round 3
// baseline (195.654 us; speedup 1.0000x reference)
//
#include <hip/hip_runtime.h>
#include <hip/hip_bf16.h>
#include <hip/hip_cooperative_groups.h>

namespace cg = cooperative_groups;

// PairwiseScore: B=2, N=256, E=512, H=150 (padded to 160)
// out[b,i,j] = (m[b,i] + m[b,j] + MLP3(g_i, g_j)) / 3
//
// Fold: hij + hj = sum_e (g_i[e]*W1c[e,h] + W1b[e,h]) * g_j[e]
// R6: SINGLE cooperative kernel. Measured fact: prep_pack + 2-kernel gap cost
// 50-65us every round -- as much as the whole main kernel. Fuse:
//   blocks 0..47  : W1a/b/c tile-transpose-pack (one [32e][150h] tile each)
//   blocks 48..54 : W2^T frag pack
//   blocks 128..255: g f32 -> bf16
//   grid.sync()
//   every block: R0's proven 53us main structure (one-shot 80KB megas,
//   async W2TF staging, shfl C->B transform; 104 VGPR, ZERO spill),
//   looped over 2 (b,i) rows per block (256 blocks = 1/CU, co-resident).
// R4/R5 lesson: acc footprint 80 f32/thread is irreducible at 512 thr;
// widening it (2-i in regs) or capping VGPR (launch_bounds ,4) => 46MB spills.
// So the main loop keeps R0's register shape EXACTLY.

typedef __attribute__((ext_vector_type(4))) float f32x4;
typedef __attribute__((ext_vector_type(4))) unsigned int u32x4;
typedef __attribute__((ext_vector_type(2))) unsigned int u32x2;
typedef __attribute__((ext_vector_type(8))) short short8;

#define NN 256
#define NE 512
#define NH 150
#define HP 160      // padded H
#define NKT 16      // NE/32 k-tiles for GEMM1
#define NHT 10      // HP/16 h-tiles
#define NS 5        // HP/32 k-steps for GEMM2

// ---------- helpers ----------
__device__ __forceinline__ unsigned pk_bf16(float a, float b) {
  unsigned ua = __builtin_bit_cast(unsigned, a);
  unsigned ub = __builtin_bit_cast(unsigned, b);
  ua += 0x7fffu + ((ua >> 16) & 1u);
  ub += 0x7fffu + ((ub >> 16) & 1u);
  return (ua >> 16) | (ub & 0xffff0000u);
}
__device__ __forceinline__ float bf_lo(unsigned u) { return __builtin_bit_cast(float, u << 16); }
__device__ __forceinline__ float bf_hi(unsigned u) { return __builtin_bit_cast(float, u & 0xffff0000u); }

__device__ __forceinline__ void async_cp16(const unsigned* gsrc, unsigned* ldst) {
  __builtin_amdgcn_global_load_lds(
      (const __attribute__((address_space(1))) unsigned*)gsrc,
      (__attribute__((address_space(3))) unsigned*)ldst, 16, 0, 0);
}

// ---------- fused cooperative kernel: 256 blocks x 512 threads ----------
__global__ __launch_bounds__(512) void fused(
    const float* __restrict__ g, const float* __restrict__ mention,
    const float* __restrict__ W1, const float* __restrict__ b1,
    const float* __restrict__ W2, const float* __restrict__ b2,
    const float* __restrict__ W3, const float* __restrict__ b3,
    unsigned short* __restrict__ g_bf16, unsigned short* __restrict__ WaF,
    unsigned short* __restrict__ WbF, unsigned short* __restrict__ WcF,
    unsigned short* __restrict__ W2TF, float* __restrict__ out)
{
  __shared__ union alignas(16) ShMem {
    float tile[32][161];                        // prep: 20.6 KB
    struct {
      unsigned int stage[8 * NHT * 64 * 4];     // 80 KB one-shot A~ mega / W2TF
      unsigned int gi[2][NE / 2];               // g_i0,g_i1 bf16 (2 KB)
      float bias1[HP];                          // b1 + hi (per current ii)
      float bias2[HP];
      float w3s[HP];
    } m;                                        // 85,888 B total
  } sh;

  const int bid = blockIdx.x, tid = threadIdx.x;
  const int lane = tid & 63, wave = tid >> 6;   // 8 waves
  const int c16 = lane & 15, quad = lane >> 4;

  // ================= prep phase (sliced across blocks) =================
  if (bid < 48) {
    // W1 pack: mat = bid>>4 (0=a,1=b,2=c), kt = bid&15; [32e][150h] tile
    int mat = bid >> 4, kt = bid & 15;
    const float* __restrict__ Wm = W1 + ((size_t)mat * NE + (size_t)kt * 32) * NH;
    for (int idx = tid; idx < 32 * NH; idx += 512) {
      int e = idx / NH, h = idx - e * NH;
      sh.tile[e][h] = Wm[idx];                  // Wm is contiguous [32][150]
    }
    for (int idx = tid; idx < 32 * 10; idx += 512)
      sh.tile[idx / 10][NH + (idx % 10)] = 0.f; // zero-pad h in [150,160)
    __syncthreads();
    unsigned short* dst = (mat == 0) ? WaF : (mat == 1) ? WbF : WcF;
    for (int row = tid; row < 640; row += 512) {  // 10 ht * 64 lanes
      int chh = row >> 6, l = row & 63;
      int el = (l >> 4) * 8, h = chh * 16 + (l & 15);
      u32x4 o;
#pragma unroll
      for (int q = 0; q < 4; ++q)
        o[q] = pk_bf16(sh.tile[el + 2 * q][h], sh.tile[el + 2 * q + 1][h]);
      ((u32x4*)dst)[kt * 640 + row] = o;
    }
  } else if (bid < 55) {
    // W2^T pack: rows 0..3199 = 5s*10ht*64lane
    int row = (bid - 48) * 512 + tid;
    if (row < 3200) {
      int s = row / 640; int rem = row - s * 640;
      int l = rem & 63; int chh = rem >> 6;
      int k = s * 32 + (l >> 4) * 8;
      int hp = chh * 16 + (l & 15);
      u32x4 o;
#pragma unroll
      for (int q = 0; q < 4; ++q) {
        int k0 = k + 2 * q, k1 = k0 + 1;
        float v0 = (k0 < NH && hp < NH) ? W2[(size_t)k0 * NH + hp] : 0.f;
        float v1 = (k1 < NH && hp < NH) ? W2[(size_t)k1 * NH + hp] : 0.f;
        o[q] = pk_bf16(v0, v1);
      }
      ((u32x4*)W2TF)[row] = o;
    }
  } else if (bid >= 128) {
    // g conversion: 65536 f32x4 over blocks 128..255 (exactly 1 per thread)
    int t = (bid - 128) * 512 + tid;
    f32x4 v = ((const f32x4*)g)[t];
    u32x2 o; o[0] = pk_bf16(v[0], v[1]); o[1] = pk_bf16(v[2], v[3]);
    ((u32x2*)g_bf16)[t] = o;
  }

  cg::this_grid().sync();   // all packed buffers visible device-wide

  // ================= main phase: 2 (b,i) rows per block =================
  const int b = bid >> 7, i0 = (bid & 127) * 2;

  // per-block constants (both i's hoisted)
  if (tid < 128) {
    int ii = tid >> 6, t = tid & 63;
    const u32x4* grow = (const u32x4*)(g_bf16 + (size_t)(b * NN + i0 + ii) * NE);
    ((u32x4*)sh.m.gi[ii])[t] = grow[t];
  }
  float b1v = 0.f;
  if (tid >= 256 && tid < 256 + HP) {
    int h = tid - 256;
    b1v = (h < NH) ? b1[h] : 0.f;
    sh.m.bias2[h] = (h < NH) ? b2[h] : 0.f;
    sh.m.w3s[h]   = (h < NH) ? W3[h] : 0.f;
  }

  const u32x4* gB = (const u32x4*)g_bf16;
  const int jbase = wave * 32 + c16;
  const size_t gidx0 = (size_t)(b * NN + jbase) * 64 + quad;  // u32x4 units
  const int lA = ((lane >> 4) & 1) * 32 + c16;  // phase-2 shfl source lanes
  const int lB = lA + 16;
  const bool selHi = ((lane >> 5) & 1) != 0;
  const float b3v = b3[0];

  // builder for one 8-kt mega-tile: exactly 10 rows/thread (5120 rows)
  auto build_mega = [&](int mega, int ii) {
#pragma unroll
    for (int r = 0; r < 10; ++r) {
      int v = tid + r * 512;                 // 0..5119
      int ktl = v / 640; int rem = v - ktl * 640;
      int l = rem & 63;
      int ktg = mega * 8 + ktl;
      int gidx = ktg * 640 + (rem >> 6) * 64 + l;
      u32x4 wb = ((const u32x4*)WbF)[gidx];
      u32x4 wc = ((const u32x4*)WcF)[gidx];
      u32x4 gi = ((const u32x4*)sh.m.gi[ii])[ktg * 4 + (l >> 4)];
      u32x4 o;
#pragma unroll
      for (int q = 0; q < 4; ++q) {
        float lo = bf_lo(gi[q]) * bf_lo(wc[q]) + bf_lo(wb[q]);
        float hi = bf_hi(gi[q]) * bf_hi(wc[q]) + bf_hi(wb[q]);
        o[q] = pk_bf16(lo, hi);
      }
      ((u32x4*)sh.m.stage)[v] = o;
    }
  };

#pragma unroll 1
  for (int ii = 0; ii < 2; ++ii) {
    // reset bias1 = b1 for this i (readers of previous ii finished pre-barrier-F)
    if (tid >= 256 && tid < 256 + HP) sh.m.bias1[tid - 256] = b1v;
    __syncthreads();   // barrier A: gi/bias ready; prev-ii stage reads done

    // ---- mega 0 build; waves 0-4 also compute hi via mini-MFMA ----
    build_mega(0, ii);
    if (wave < 5) {
      f32x4 ah0 = {}, ah1 = {};
#pragma unroll
      for (int kt = 0; kt < NKT; ++kt) {
        short8 bbc = __builtin_bit_cast(short8, ((const u32x4*)sh.m.gi[ii])[kt * 4 + quad]);
        short8 a0 = __builtin_bit_cast(short8,
            ((const u32x4*)WaF)[(kt * NHT + 2 * wave) * 64 + lane]);
        short8 a1 = __builtin_bit_cast(short8,
            ((const u32x4*)WaF)[(kt * NHT + 2 * wave + 1) * 64 + lane]);
        ah0 = __builtin_amdgcn_mfma_f32_16x16x32_bf16(a0, bbc, ah0, 0, 0, 0);
        ah1 = __builtin_amdgcn_mfma_f32_16x16x32_bf16(a1, bbc, ah1, 0, 0, 0);
      }
      if (c16 == 0) {
#pragma unroll
        for (int r = 0; r < 4; ++r) {
          sh.m.bias1[(2 * wave) * 16 + quad * 4 + r]     += ah0[r];
          sh.m.bias1[(2 * wave + 1) * 16 + quad * 4 + r] += ah1[r];
        }
      }
    }
    __syncthreads();   // barrier B: mega-0 A~ + bias1 ready

    // ---- phase 1: D1[h][j] = A~ * g_j, two barrier-pair mega-phases ----
    f32x4 acc1[NHT][2] = {};
#pragma unroll 1
    for (int mega = 0; mega < 2; ++mega) {
#pragma unroll 1
      for (int ktl = 0; ktl < 8; ++ktl) {
        int ktg = mega * 8 + ktl;
        short8 bf0 = __builtin_bit_cast(short8, gB[gidx0 + (size_t)ktg * 4]);
        short8 bf1 = __builtin_bit_cast(short8, gB[gidx0 + 16 * 64 + (size_t)ktg * 4]);
        const u32x4* As = (const u32x4*)sh.m.stage + ktl * (NHT * 64);
#pragma unroll
        for (int ht = 0; ht < NHT; ++ht) {
          short8 af = __builtin_bit_cast(short8, As[ht * 64 + lane]);
          acc1[ht][0] = __builtin_amdgcn_mfma_f32_16x16x32_bf16(af, bf0, acc1[ht][0], 0, 0, 0);
          acc1[ht][1] = __builtin_amdgcn_mfma_f32_16x16x32_bf16(af, bf1, acc1[ht][1], 0, 0, 0);
        }
      }
      if (mega == 0) {
        __syncthreads();   // barrier C: mega-0 reads done
        build_mega(1, ii);
        __syncthreads();   // barrier D: mega-1 A~ ready
      }
    }
    __syncthreads();       // barrier E: all stage reads done (free for W2TF)

    // ---- stage W2^T frags async into freed buffer; overlap epilogue ----
#pragma unroll
    for (int r = 0; r < 7; ++r) {
      int row = tid + r * 512;
      if (row < 3200)
        async_cp16((const unsigned*)W2TF + (size_t)row * 4, sh.m.stage + row * 4);
    }

    // ---- epilogue 1: h1 = relu(D1 + hi + b1) -> bf16 in registers ----
    unsigned Hlo[NHT][2], Hhi[NHT][2];
#pragma unroll
    for (int ht = 0; ht < NHT; ++ht) {
      f32x4 bv = *(const f32x4*)(sh.m.bias1 + ht * 16 + quad * 4);
#pragma unroll
      for (int jt = 0; jt < 2; ++jt) {
        f32x4 v = acc1[ht][jt];
        float r0 = fmaxf(v[0] + bv[0], 0.f);
        float r1 = fmaxf(v[1] + bv[1], 0.f);
        float r2 = fmaxf(v[2] + bv[2], 0.f);
        float r3 = fmaxf(v[3] + bv[3], 0.f);
        Hlo[ht][jt] = pk_bf16(r0, r1);
        Hhi[ht][jt] = pk_bf16(r2, r3);
      }
    }
    __syncthreads();       // barrier F: drains async staging

    // ---- phase 2: D2[h'][j] = W2^T * h1 ; C-layout -> B-frag via shfl ----
    f32x4 acc2[NHT][2] = {};
#pragma unroll
    for (int s = 0; s < NS; ++s) {
      short8 b2f[2];
#pragma unroll
      for (int jt = 0; jt < 2; ++jt) {
        unsigned a0 = (unsigned)__shfl((int)Hlo[2 * s][jt], lA);
        unsigned a1 = (unsigned)__shfl((int)Hhi[2 * s][jt], lA);
        unsigned a2 = (unsigned)__shfl((int)Hlo[2 * s][jt], lB);
        unsigned a3 = (unsigned)__shfl((int)Hhi[2 * s][jt], lB);
        unsigned d0 = (unsigned)__shfl((int)Hlo[2 * s + 1][jt], lA);
        unsigned d1 = (unsigned)__shfl((int)Hhi[2 * s + 1][jt], lA);
        unsigned d2 = (unsigned)__shfl((int)Hlo[2 * s + 1][jt], lB);
        unsigned d3 = (unsigned)__shfl((int)Hhi[2 * s + 1][jt], lB);
        u32x4 fr;
        fr[0] = selHi ? d0 : a0;
        fr[1] = selHi ? d1 : a1;
        fr[2] = selHi ? d2 : a2;
        fr[3] = selHi ? d3 : a3;
        b2f[jt] = __builtin_bit_cast(short8, fr);
      }
      const u32x4* A2 = (const u32x4*)sh.m.stage + s * (NHT * 64);
#pragma unroll
      for (int ht = 0; ht < NHT; ++ht) {
        short8 af = __builtin_bit_cast(short8, A2[ht * 64 + lane]);
        acc2[ht][0] = __builtin_amdgcn_mfma_f32_16x16x32_bf16(af, b2f[0], acc2[ht][0], 0, 0, 0);
        acc2[ht][1] = __builtin_amdgcn_mfma_f32_16x16x32_bf16(af, b2f[1], acc2[ht][1], 0, 0, 0);
      }
    }

    // ---- epilogue 2 + GEMM3: score[j] = sum_h' relu(D2 + b2)*W3 ----
    float part0 = 0.f, part1 = 0.f;
#pragma unroll
    for (int ht = 0; ht < NHT; ++ht) {
      f32x4 bv = *(const f32x4*)(sh.m.bias2 + ht * 16 + quad * 4);
      f32x4 wv = *(const f32x4*)(sh.m.w3s + ht * 16 + quad * 4);
      f32x4 v0 = acc2[ht][0], v1 = acc2[ht][1];
#pragma unroll
      for (int r = 0; r < 4; ++r) {
        part0 += fmaxf(v0[r] + bv[r], 0.f) * wv[r];
        part1 += fmaxf(v1[r] + bv[r], 0.f) * wv[r];
      }
    }
    part0 += __shfl_xor(part0, 16); part0 += __shfl_xor(part0, 32);
    part1 += __shfl_xor(part1, 16); part1 += __shfl_xor(part1, 32);

    const float mi = mention[b * NN + i0 + ii];
    float sc = (quad == 0) ? part0 : part1;
    if (quad < 2) {
      int j = wave * 32 + quad * 16 + c16;
      float mj = mention[b * NN + j];
      out[((size_t)(b * NN + i0 + ii)) * NN + j] = (mi + mj + sc + b3v) * (1.f / 3.f);
    }
  }
}

// ---------- launch ----------
extern "C" void kernel_launch(void* const* d_in, const int* in_sizes, int n_in,
                              void* d_out, int out_size, void* d_ws, size_t ws_size,
                              hipStream_t stream) {
  const float* g  = (const float*)d_in[0];
  const float* m  = (const float*)d_in[1];
  const float* W1 = (const float*)d_in[2];
  const float* b1 = (const float*)d_in[3];
  const float* W2 = (const float*)d_in[4];
  const float* b2 = (const float*)d_in[5];
  const float* W3 = (const float*)d_in[6];
  const float* b3 = (const float*)d_in[7];
  float* out = (float*)d_out;

  char* ws = (char*)d_ws;
  unsigned short* g_bf16 = (unsigned short*)(ws);              // 524288 B
  unsigned short* WaF    = (unsigned short*)(ws + 524288);     // 163840 B
  unsigned short* WbF    = (unsigned short*)(ws + 688128);     // 163840 B
  unsigned short* WcF    = (unsigned short*)(ws + 851968);     // 163840 B
  unsigned short* W2TF   = (unsigned short*)(ws + 1015808);    //  51200 B (total ~1.02 MB)

  void* args[] = {(void*)&g, (void*)&m, (void*)&W1, (void*)&b1,
                  (void*)&W2, (void*)&b2, (void*)&W3, (void*)&b3,
                  (void*)&g_bf16, (void*)&WaF, (void*)&WbF, (void*)&WcF,
                  (void*)&W2TF, (void*)&out};
  hipLaunchCooperativeKernel((const void*)fused, dim3(256), dim3(512),
                             args, 0, stream);
}

// Round 4
// 124.845 us; speedup vs baseline: 1.5672x; 1.5672x over previous
//
#include <hip/hip_runtime.h>
#include <hip/hip_bf16.h>

// PairwiseScore: B=2, N=256, E=512, H=150 (padded to 160)
// out[b,i,j] = (m[b,i] + m[b,j] + MLP3(g_i, g_j)) / 3
//
// Fold: hij + hj = sum_e (g_i[e]*W1c[e,h] + W1b[e,h]) * g_j[e]
// R7 = R0's proven structure (104 VGPR, zero spill) with ONE change:
//   stage shrunk 8kt(80KB) -> 6kt(60KB), megas {6,5,5}. Total LDS ~64.4KB
//   => TWO blocks/CU co-resident (was 1), 512 blocks in ONE overlapped round
//   (was 2 sequential). Partner block fills barrier/build stalls.
// Lessons enforced (R4/R5/R6 of prior rounds):
//   - keep R0 register shape EXACTLY (acc1 80 f32 -> reuse -> acc2 80);
//     any widening or launch_bounds cap => 33-46MB scratch spills.
//   - no cooperative launch (measured +90us non-kernel overhead).
// prep: W1 pack via 96 half-tile LDS transposes (coalesced, bank-padded).

typedef __attribute__((ext_vector_type(4))) float f32x4;
typedef __attribute__((ext_vector_type(4))) unsigned int u32x4;
typedef __attribute__((ext_vector_type(2))) unsigned int u32x2;
typedef __attribute__((ext_vector_type(8))) short short8;

#define NN 256
#define NE 512
#define NH 150
#define HP 160      // padded H
#define NKT 16      // NE/32 k-tiles for GEMM1
#define NHT 10      // HP/16 h-tiles
#define NS 5        // HP/32 k-steps for GEMM2
#define STKT 6      // k-tiles in the A~ stage buffer (megas {6,5,5})

// ---------- helpers ----------
__device__ __forceinline__ unsigned pk_bf16(float a, float b) {
  unsigned ua = __builtin_bit_cast(unsigned, a);
  unsigned ub = __builtin_bit_cast(unsigned, b);
  ua += 0x7fffu + ((ua >> 16) & 1u);
  ub += 0x7fffu + ((ub >> 16) & 1u);
  return (ua >> 16) | (ub & 0xffff0000u);
}
__device__ __forceinline__ float bf_lo(unsigned u) { return __builtin_bit_cast(float, u << 16); }
__device__ __forceinline__ float bf_hi(unsigned u) { return __builtin_bit_cast(float, u & 0xffff0000u); }

__device__ __forceinline__ void async_cp16(const unsigned* gsrc, unsigned* ldst) {
  __builtin_amdgcn_global_load_lds(
      (const __attribute__((address_space(1))) unsigned*)gsrc,
      (__attribute__((address_space(3))) unsigned*)ldst, 16, 0, 0);
}

// ---------- prep: grid 365 x 256 ----------
//  bid [0,256)   : g (f32) -> g_bf16
//  bid [256,352) : W1a/b/c -> frag-major via half-tile LDS transpose
//                  (mat = bb/32, kt = (bb%32)>>1, half = bb&1)
//  bid [352,365) : W2^T -> W2TF frag-major [(s*10+ht)*64+lane]*8
__global__ __launch_bounds__(256) void prep_pack(
    const float* __restrict__ g, const float* __restrict__ W1,
    const float* __restrict__ W2,
    unsigned short* __restrict__ g_bf16, unsigned short* __restrict__ WaF,
    unsigned short* __restrict__ WbF, unsigned short* __restrict__ WcF,
    unsigned short* __restrict__ W2TF)
{
  __shared__ float tile[16][161];   // 16 e-rows x (150 h + 10 zero-pad + 1 bank pad)
  int bid = blockIdx.x, tid = threadIdx.x;
  if (bid < 256) {
    int t = bid * 256 + tid;                 // 65536 float4s = 262144 floats
    f32x4 v = ((const f32x4*)g)[t];
    u32x2 o; o[0] = pk_bf16(v[0], v[1]); o[1] = pk_bf16(v[2], v[3]);
    ((u32x2*)g_bf16)[t] = o;
  } else if (bid < 352) {
    int bb = bid - 256;
    int mat = bb >> 5;                       // 0=a,1=b,2=c
    int kt = (bb & 31) >> 1;                 // 0..15
    int half = bb & 1;                       // e-halves [0,16) / [16,32)
    const float* __restrict__ Wm =
        W1 + ((size_t)mat * NE + (size_t)kt * 32 + (size_t)half * 16) * NH;
    // coalesced load of the [16 e][150 h] half-tile
    for (int idx = tid; idx < 16 * NH; idx += 256) {
      int e = idx / NH, h = idx - e * NH;
      tile[e][h] = Wm[idx];                  // Wm contiguous [16][150]
    }
    for (int idx = tid; idx < 16 * 10; idx += 256)
      tile[idx / 10][NH + (idx % 10)] = 0.f; // zero h in [150,160)
    __syncthreads();
    unsigned short* dst = (mat == 0) ? WaF : (mat == 1) ? WbF : WcF;
#pragma unroll
    for (int r = 0; r < 2; ++r) {
      int rr = tid + r * 256;                // 0..319: this half's frag rows
      if (rr < 320) {
        int chh = rr >> 5;                   // 0..9
        int l = half * 32 + (rr & 31);       // lanes with (l>>5)==half
        int el = ((l >> 4) & 1) * 8;         // local e-offset in [0,16)
        int h = chh * 16 + (l & 15);
        u32x4 o;
#pragma unroll
        for (int q = 0; q < 4; ++q)
          o[q] = pk_bf16(tile[el + 2 * q][h], tile[el + 2 * q + 1][h]);
        ((u32x4*)dst)[kt * 640 + chh * 64 + l] = o;
      }
    }
  } else {
    int row = (bid - 352) * 256 + tid;       // < 3200 = 5s*10ht*64lane
    if (row < 3200) {
      int s = row / 640; int rem = row - s * 640;
      int l = rem & 63; int chh = rem >> 6;
      int k = s * 32 + (l >> 4) * 8;
      int hp = chh * 16 + (l & 15);
      u32x4 o;
#pragma unroll
      for (int q = 0; q < 4; ++q) {
        int k0 = k + 2 * q, k1 = k0 + 1;
        float v0 = (k0 < NH && hp < NH) ? W2[(size_t)k0 * NH + hp] : 0.f;
        float v1 = (k1 < NH && hp < NH) ? W2[(size_t)k1 * NH + hp] : 0.f;
        o[q] = pk_bf16(v0, v1);
      }
      ((u32x4*)W2TF)[row] = o;
    }
  }
}

// ---------- main fused kernel: 512 threads, one block per (b,i) ----------
__global__ __launch_bounds__(512) void pair_main(
    const float* __restrict__ mention, const float* __restrict__ b1,
    const float* __restrict__ b2, const float* __restrict__ W3,
    const float* __restrict__ b3,
    const unsigned short* __restrict__ g_bf16,
    const unsigned short* __restrict__ WaF,
    const unsigned short* __restrict__ WbF, const unsigned short* __restrict__ WcF,
    const unsigned short* __restrict__ W2TF,
    float* __restrict__ out)
{
  __shared__ unsigned int stage[STKT * NHT * 64 * 4];  // 60 KB: A~ mega-tile / W2TF
  __shared__ unsigned int gi_lds[NE / 2];              // g_i as bf16 (1 KB)
  __shared__ alignas(16) float bias1[HP];              // b1 + hi (hi via mini-MFMA)
  __shared__ alignas(16) float bias2[HP];
  __shared__ alignas(16) float w3s[HP];

  const int tid = threadIdx.x;
  const int bi = blockIdx.x;
  const int b = bi >> 8, i = bi & 255;
  const int lane = tid & 63, wave = tid >> 6;       // 8 waves
  const int c16 = lane & 15, quad = lane >> 4;

  // ---- phase 0: per-block constants into LDS ----
  {
    const u32x4* grow = (const u32x4*)(g_bf16 + (size_t)(b * NN + i) * NE);
    if (tid < 64) ((u32x4*)gi_lds)[tid] = grow[tid];
    if (tid < HP) {
      int h = tid;
      bias1[h] = (h < NH) ? b1[h] : 0.f;
      bias2[h] = (h < NH) ? b2[h] : 0.f;
      w3s[h]   = (h < NH) ? W3[h] : 0.f;
    }
  }
  __syncthreads();   // barrier A

  // ---- builder for a mega-tile of `count` k-tiles starting at `start` ----
  auto build_mega = [&](int start, int count) {
    int rows = count * 640;
#pragma unroll
    for (int r = 0; r < 8; ++r) {
      int v = tid + r * 512;                 // up to 4095; rows <= 3840
      if (v < rows) {
        int ktl = v / 640; int rem = v - ktl * 640;
        int l = rem & 63;
        int ktg = start + ktl;
        int gidx = ktg * 640 + (rem >> 6) * 64 + l;
        u32x4 wb = ((const u32x4*)WbF)[gidx];
        u32x4 wc = ((const u32x4*)WcF)[gidx];
        u32x4 gi = ((const u32x4*)gi_lds)[ktg * 4 + (l >> 4)];
        u32x4 o;
#pragma unroll
        for (int q = 0; q < 4; ++q) {
          float lo = bf_lo(gi[q]) * bf_lo(wc[q]) + bf_lo(wb[q]);
          float hi = bf_hi(gi[q]) * bf_hi(wc[q]) + bf_hi(wb[q]);
          o[q] = pk_bf16(lo, hi);
        }
        ((u32x4*)stage)[v] = o;
      }
    }
  };

  // ---- mega 0 build; waves 0-4 also compute hi via mini-MFMA (broadcast B) ----
  build_mega(0, 6);
  if (wave < 5) {
    f32x4 ah0 = {}, ah1 = {};
#pragma unroll
    for (int kt = 0; kt < NKT; ++kt) {
      short8 bbc = __builtin_bit_cast(short8, ((const u32x4*)gi_lds)[kt * 4 + quad]);
      short8 a0 = __builtin_bit_cast(short8,
          ((const u32x4*)WaF)[(kt * NHT + 2 * wave) * 64 + lane]);
      short8 a1 = __builtin_bit_cast(short8,
          ((const u32x4*)WaF)[(kt * NHT + 2 * wave + 1) * 64 + lane]);
      ah0 = __builtin_amdgcn_mfma_f32_16x16x32_bf16(a0, bbc, ah0, 0, 0, 0);
      ah1 = __builtin_amdgcn_mfma_f32_16x16x32_bf16(a1, bbc, ah1, 0, 0, 0);
    }
    if (c16 == 0) {
#pragma unroll
      for (int r = 0; r < 4; ++r) {
        bias1[(2 * wave) * 16 + quad * 4 + r]     += ah0[r];
        bias1[(2 * wave + 1) * 16 + quad * 4 + r] += ah1[r];
      }
    }
  }
  __syncthreads();   // barrier B: mega-0 A~ + bias1 ready

  // ---- phase 1: D1[h][j] = A~ * g_j over megas {6,5,5} ----
  f32x4 acc1[NHT][2] = {};
  const u32x4* gB = (const u32x4*)g_bf16;
  const int jbase = wave * 32 + c16;
  const size_t gidx0 = (size_t)(b * NN + jbase) * 64 + quad;  // u32x4 units

  auto gemm1_phase = [&](int start, int count) {
#pragma unroll 1
    for (int ktl = 0; ktl < count; ++ktl) {
      int ktg = start + ktl;
      short8 bf0 = __builtin_bit_cast(short8, gB[gidx0 + (size_t)ktg * 4]);
      short8 bf1 = __builtin_bit_cast(short8, gB[gidx0 + 16 * 64 + (size_t)ktg * 4]);
      const u32x4* As = (const u32x4*)stage + ktl * (NHT * 64);
#pragma unroll
      for (int ht = 0; ht < NHT; ++ht) {
        short8 af = __builtin_bit_cast(short8, As[ht * 64 + lane]);
        acc1[ht][0] = __builtin_amdgcn_mfma_f32_16x16x32_bf16(af, bf0, acc1[ht][0], 0, 0, 0);
        acc1[ht][1] = __builtin_amdgcn_mfma_f32_16x16x32_bf16(af, bf1, acc1[ht][1], 0, 0, 0);
      }
    }
  };

  gemm1_phase(0, 6);
  __syncthreads();   // mega-0 reads done
  build_mega(6, 5);
  __syncthreads();   // mega-1 A~ ready
  gemm1_phase(6, 5);
  __syncthreads();   // mega-1 reads done
  build_mega(11, 5);
  __syncthreads();   // mega-2 A~ ready
  gemm1_phase(11, 5);
  __syncthreads();   // barrier E: all stage reads done (free buffer for W2TF)

  // ---- stage W2^T frags async (3200 rows) into freed buffer; overlap epilogue ----
#pragma unroll
  for (int r = 0; r < 7; ++r) {
    int row = tid + r * 512;
    if (row < 3200)
      async_cp16((const unsigned*)W2TF + (size_t)row * 4, stage + row * 4);
  }

  // ---- epilogue 1: h1 = relu(D1 + hi + b1) -> bf16 in registers ----
  // lane holds h = 16*ht + 4*quad + r, j = wave*32 + jt*16 + c16
  unsigned Hlo[NHT][2], Hhi[NHT][2];
#pragma unroll
  for (int ht = 0; ht < NHT; ++ht) {
    f32x4 bv = *(const f32x4*)(bias1 + ht * 16 + quad * 4);
#pragma unroll
    for (int jt = 0; jt < 2; ++jt) {
      f32x4 v = acc1[ht][jt];
      float r0 = fmaxf(v[0] + bv[0], 0.f);
      float r1 = fmaxf(v[1] + bv[1], 0.f);
      float r2 = fmaxf(v[2] + bv[2], 0.f);
      float r3 = fmaxf(v[3] + bv[3], 0.f);
      Hlo[ht][jt] = pk_bf16(r0, r1);
      Hhi[ht][jt] = pk_bf16(r2, r3);
    }
  }
  __syncthreads();       // barrier F: drains async staging

  // ---- phase 2: D2[h'][j] = W2^T * h1 ; h1 C-layout -> B-frag via shfl ----
  f32x4 acc2[NHT][2] = {};
  const int lA = ((lane >> 4) & 1) * 32 + c16;  // source lane for d0..3
  const int lB = lA + 16;                        // source lane for d4..7
  const bool selHi = ((lane >> 5) & 1) != 0;     // quads 2,3 take t=2s+1

#pragma unroll
  for (int s = 0; s < NS; ++s) {
    short8 b2f[2];
#pragma unroll
    for (int jt = 0; jt < 2; ++jt) {
      unsigned a0 = (unsigned)__shfl((int)Hlo[2 * s][jt], lA);
      unsigned a1 = (unsigned)__shfl((int)Hhi[2 * s][jt], lA);
      unsigned a2 = (unsigned)__shfl((int)Hlo[2 * s][jt], lB);
      unsigned a3 = (unsigned)__shfl((int)Hhi[2 * s][jt], lB);
      unsigned d0 = (unsigned)__shfl((int)Hlo[2 * s + 1][jt], lA);
      unsigned d1 = (unsigned)__shfl((int)Hhi[2 * s + 1][jt], lA);
      unsigned d2 = (unsigned)__shfl((int)Hlo[2 * s + 1][jt], lB);
      unsigned d3 = (unsigned)__shfl((int)Hhi[2 * s + 1][jt], lB);
      u32x4 fr;
      fr[0] = selHi ? d0 : a0;
      fr[1] = selHi ? d1 : a1;
      fr[2] = selHi ? d2 : a2;
      fr[3] = selHi ? d3 : a3;
      b2f[jt] = __builtin_bit_cast(short8, fr);
    }
    const u32x4* A2 = (const u32x4*)stage + s * (NHT * 64);
#pragma unroll
    for (int ht = 0; ht < NHT; ++ht) {
      short8 af = __builtin_bit_cast(short8, A2[ht * 64 + lane]);
      acc2[ht][0] = __builtin_amdgcn_mfma_f32_16x16x32_bf16(af, b2f[0], acc2[ht][0], 0, 0, 0);
      acc2[ht][1] = __builtin_amdgcn_mfma_f32_16x16x32_bf16(af, b2f[1], acc2[ht][1], 0, 0, 0);
    }
  }

  // ---- epilogue 2 + GEMM3: score[j] = sum_h' relu(D2 + b2)*W3 ----
  float part0 = 0.f, part1 = 0.f;
#pragma unroll
  for (int ht = 0; ht < NHT; ++ht) {
    f32x4 bv = *(const f32x4*)(bias2 + ht * 16 + quad * 4);
    f32x4 wv = *(const f32x4*)(w3s + ht * 16 + quad * 4);
    f32x4 v0 = acc2[ht][0], v1 = acc2[ht][1];
#pragma unroll
    for (int r = 0; r < 4; ++r) {
      part0 += fmaxf(v0[r] + bv[r], 0.f) * wv[r];
      part1 += fmaxf(v1[r] + bv[r], 0.f) * wv[r];
    }
  }
  part0 += __shfl_xor(part0, 16); part0 += __shfl_xor(part0, 32);
  part1 += __shfl_xor(part1, 16); part1 += __shfl_xor(part1, 32);

  const float mi = mention[b * NN + i];
  const float b3v = b3[0];
  float sc = (quad == 0) ? part0 : part1;
  if (quad < 2) {
    int j = wave * 32 + quad * 16 + c16;
    float mj = mention[b * NN + j];
    out[((size_t)(b * NN + i)) * NN + j] = (mi + mj + sc + b3v) * (1.f / 3.f);
  }
}

// ---------- launch ----------
extern "C" void kernel_launch(void* const* d_in, const int* in_sizes, int n_in,
                              void* d_out, int out_size, void* d_ws, size_t ws_size,
                              hipStream_t stream) {
  const float* g  = (const float*)d_in[0];
  const float* m  = (const float*)d_in[1];
  const float* W1 = (const float*)d_in[2];
  const float* b1 = (const float*)d_in[3];
  const float* W2 = (const float*)d_in[4];
  const float* b2 = (const float*)d_in[5];
  const float* W3 = (const float*)d_in[6];
  const float* b3 = (const float*)d_in[7];
  float* out = (float*)d_out;

  char* ws = (char*)d_ws;
  unsigned short* g_bf16 = (unsigned short*)(ws);              // 524288 B
  unsigned short* WaF    = (unsigned short*)(ws + 524288);     // 163840 B
  unsigned short* WbF    = (unsigned short*)(ws + 688128);     // 163840 B
  unsigned short* WcF    = (unsigned short*)(ws + 851968);     // 163840 B
  unsigned short* W2TF   = (unsigned short*)(ws + 1015808);    //  51200 B (total ~1.02 MB)

  prep_pack<<<365, 256, 0, stream>>>(g, W1, W2, g_bf16, WaF, WbF, WcF, W2TF);
  pair_main<<<512, 512, 0, stream>>>(m, b1, b2, W3, b3, g_bf16, WaF, WbF, WcF, W2TF, out);
}